// Round 16
// baseline (194.708 us; speedup 1.0000x reference)
//
#include <hip/hip_runtime.h>
#include <hip/hip_bf16.h>

typedef __attribute__((ext_vector_type(8))) short short8;
typedef __attribute__((ext_vector_type(4))) float f32x4;
typedef __attribute__((ext_vector_type(2))) float f32x2;

#define DEVI __device__ __forceinline__

static constexpr int NB = 4;
static constexpr int NN = 4096;
static constexpr int NE = 65536;
static constexpr int MROWS = NB * NN; // 16384

DEVI short f2b(float f) {
    __hip_bfloat16 h = __float2bfloat16(f);
    return *reinterpret_cast<short*>(&h);
}
DEVI float b2f(ushort u) {
    uint v = (uint)u << 16;
    float f;
    __builtin_memcpy(&f, &v, 4);
    return f;
}

// ---------------- prep: fp32 -> bf16 weights ----------------
// order: [0]=W_src_gate [1]=W_dst_gate [2]=W_dst_update [3]=W_src_update [4]=W_edge_gate
__global__ void prep_weights(const float* __restrict__ w0, const float* __restrict__ w1,
                             const float* __restrict__ w2, const float* __restrict__ w3,
                             const float* __restrict__ w4, ushort* __restrict__ out) {
    int idx = blockIdx.x * 256 + threadIdx.x;   // 5*16384 total
    int wsel = idx >> 14;
    int off = idx & 16383;
    const float* src = wsel == 0 ? w0 : wsel == 1 ? w1 : wsel == 2 ? w2 : wsel == 3 ? w3 : w4;
    out[idx] = (ushort)f2b(src[off]);
}

// ---------------- counting sort of edges by destination i ----------------
__global__ void hist_kernel(const int* __restrict__ iIdx, int* __restrict__ cnt) {
    int e = blockIdx.x * 256 + threadIdx.x;
    atomicAdd(&cnt[iIdx[e]], 1);
}

__global__ __launch_bounds__(256) void scan_kernel(const int* __restrict__ cnt,
                                                   int* __restrict__ start) {
    __shared__ int ls[256];
    int t = threadIdx.x;
    int base = t * 16;
    int loc[16];
    int s = 0;
#pragma unroll
    for (int q = 0; q < 16; ++q) { loc[q] = s; s += cnt[base + q]; }
    ls[t] = s;
    __syncthreads();
    for (int off = 1; off < 256; off <<= 1) {
        int v = (t >= off) ? ls[t - off] : 0;
        __syncthreads();
        ls[t] += v;
        __syncthreads();
    }
    int ex = ls[t] - s;   // exclusive prefix of this thread's chunk
#pragma unroll
    for (int q = 0; q < 16; ++q) start[base + q] = ex + loc[q];
    if (t == 255) start[4096] = ex + s;
}

// rank[e] = sorted position of edge e; jsort[pos] = jIdx[e]
__global__ void scatter_kernel(const int* __restrict__ iIdx, const int* __restrict__ jIdx,
                               const int* __restrict__ start, int* __restrict__ cur,
                               int* __restrict__ rank, int* __restrict__ jsort) {
    int e = blockIdx.x * 256 + threadIdx.x;
    int iv = iIdx[e];
    int pos = start[iv] + atomicAdd(&cur[iv], 1);
    rank[e] = pos;
    jsort[pos] = jIdx[e];
}

// Stage one 128x128 bf16 weight into LDS, XOR-swizzled (byte ^= (n&7)<<4). 256 threads.
DEVI void stage_W256(const ushort* __restrict__ Wg, ushort* Wl, int tid) {
    int n = tid >> 1;           // row 0..127
    int kh = (tid & 1) * 64;    // half-row in bf16 elems
#pragma unroll
    for (int c = 0; c < 8; ++c) {
        int k = kh + c * 8;
        short8 v = *reinterpret_cast<const short8*>(Wg + n * 128 + k);
        int byt = (n * 256 + k * 2) ^ ((n & 7) << 4);
        *reinterpret_cast<short8*>(reinterpret_cast<char*>(Wl) + byt) = v;
    }
}

// Load this lane's A fragments (K=128 split in 4 ks-slices) from a fp32 row.
DEVI void load_afrag(const float* __restrict__ rowptr, int kgrp, short8 afrag[4]) {
#pragma unroll
    for (int ks = 0; ks < 4; ++ks) {
        int k0 = ks * 32 + kgrp * 8;
        f32x4 lo = *reinterpret_cast<const f32x4*>(rowptr + k0);
        f32x4 hi = *reinterpret_cast<const f32x4*>(rowptr + k0 + 4);
        short8 a;
#pragma unroll
        for (int q = 0; q < 4; ++q) a[q] = f2b(lo[q]);
#pragma unroll
        for (int q = 0; q < 4; ++q) a[4 + q] = f2b(hi[q]);
        afrag[ks] = a;
    }
}

// acc[nt]: row = wv*16 + (lane>>4)*4 + r, col = nt*16 + (lane&15). B from XOR-swizzled LDS.
DEVI void mfma_frags(const short8 afrag[4], const ushort* __restrict__ Wl,
                     int lane, f32x4 acc[8]) {
    const int colb = lane & 15;
    const int kgrp = lane >> 4;
#pragma unroll
    for (int nt = 0; nt < 8; ++nt) acc[nt] = f32x4{0.f, 0.f, 0.f, 0.f};
#pragma unroll
    for (int ks = 0; ks < 4; ++ks) {
#pragma unroll
        for (int nt = 0; nt < 8; ++nt) {
            int n = nt * 16 + colb;
            int byt = (n * 256 + (ks * 32 + kgrp * 8) * 2) ^ ((n & 7) << 4);
            short8 bfrag = *reinterpret_cast<const short8*>(
                reinterpret_cast<const char*>(Wl) + byt);
            acc[nt] = __builtin_amdgcn_mfma_f32_16x16x32_bf16(afrag[ks], bfrag, acc[nt], 0, 0, 0);
        }
    }
}

// MFMA with B fragments read DIRECTLY from global bf16 W [128][128] (L1-resident).
// Round-9-proven semantics.
DEVI void mfma_frags_g(const short8 afrag[4], const ushort* __restrict__ Wg,
                       int lane, f32x4 acc[8]) {
    const int colb = lane & 15;
    const int kgrp = lane >> 4;
#pragma unroll
    for (int nt = 0; nt < 8; ++nt) acc[nt] = f32x4{0.f, 0.f, 0.f, 0.f};
#pragma unroll
    for (int ks = 0; ks < 4; ++ks) {
#pragma unroll
        for (int nt = 0; nt < 8; ++nt) {
            const short8 bfrag = *reinterpret_cast<const short8*>(
                Wg + (nt * 16 + colb) * 128 + ks * 32 + kgrp * 8);
            acc[nt] = __builtin_amdgcn_mfma_f32_16x16x32_bf16(afrag[ks], bfrag, acc[nt], 0, 0, 0);
        }
    }
}

// ---------------- node projections: P[w] = bf16(node_feats @ W[w]^T + b[w]) ----------------
// Round-6/10/12 proven version (LDS-staged W, blockIdx.y = weight index).
__global__ __launch_bounds__(256) void node_proj_kernel(
    const float* __restrict__ node_feats,  // [MROWS,128]
    const ushort* __restrict__ Wbf,        // [5][128][128] bf16
    const float* __restrict__ bias0, const float* __restrict__ bias1,
    const float* __restrict__ bias2, const float* __restrict__ bias3,
    ushort* __restrict__ P)                // [4][MROWS][128] bf16
{
    __shared__ ushort Wl[128 * 128];  // 32 KB
    const int widx = blockIdx.y;
    const int row0 = blockIdx.x * 64;
    const int tid = threadIdx.x;

    stage_W256(Wbf + (size_t)widx * 16384, Wl, tid);
    __syncthreads();

    const int lane = tid & 63, wv = tid >> 6;
    const int colb = lane & 15, kgrp = lane >> 4;
    short8 afrag[4];
    load_afrag(node_feats + (size_t)(row0 + wv * 16 + colb) * 128, kgrp, afrag);
    f32x4 acc[8];
    mfma_frags(afrag, Wl, lane, acc);

    const float* bias = widx == 0 ? bias0 : widx == 1 ? bias1 : widx == 2 ? bias2 : bias3;
    ushort* Po = P + (size_t)widx * MROWS * 128;
#pragma unroll
    for (int r = 0; r < 4; ++r) {
        int row = row0 + wv * 16 + kgrp * 4 + r;
#pragma unroll
        for (int nt = 0; nt < 8; ++nt) {
            int col = nt * 16 + colb;
            Po[(size_t)row * 128 + col] = (ushort)f2b(acc[nt][r] + bias[col]);
        }
    }
}

// ---------------- fused edge kernel: 256-thread, NO LDS, NO barrier, W direct-from-global ----------------
// Single delta vs round 15: small blocks + direct-global W (round-9-proven semantics), natural
// register footprint (~84 incl AGPR, NO cap -> no spill). blocks/CU = floor(5 waves/SIMD x4 /4) = 5
// -> ~20 waves/CU vs 12 for the 512-thread LDS version.
__global__ __launch_bounds__(256) void edge_kernel(
    const float* __restrict__ edge_feats,  // [NB,NE,128]
    const int* __restrict__ iIdx, const int* __restrict__ jIdx,
    const int* __restrict__ rank,          // [NE] sorted position of edge e
    const ushort* __restrict__ Weg,        // [128][128] bf16 (edge gate)
    const float* __restrict__ b_eg,
    const ushort* __restrict__ Psg, const ushort* __restrict__ Pdg,
    uchar* __restrict__ sigF8,             // [NB,NE,128] fp8 e4m3, SORTED edge order
    float* __restrict__ yOut)              // [NB,NE,128]
{
    const int b = blockIdx.y;
    const int e0 = blockIdx.x * 64;
    const int tid = threadIdx.x;
    const int lane = tid & 63, wv = tid >> 6;   // wv 0..3
    const int colb = lane & 15, kgrp = lane >> 4;
    const float* Ab = edge_feats + (size_t)b * NE * 128;
    const size_t nbase = (size_t)b * NN;

    short8 afrag[4];
    load_afrag(Ab + (size_t)(e0 + wv * 16 + colb) * 128, kgrp, afrag);

    // hoisted epilogue indices
    int eA[4], iA[4], jA[4], rkA[4];
#pragma unroll
    for (int r = 0; r < 4; ++r) {
        int e = e0 + wv * 16 + kgrp * 4 + r;
        eA[r] = e;
        iA[r] = iIdx[e];
        jA[r] = jIdx[e];
        rkA[r] = rank[e];
    }

    f32x4 acc[8];
    mfma_frags_g(afrag, Weg, lane, acc);

    // epilogue in fragment layout (round-2/5/6/12/15 proven)
#pragma unroll
    for (int r = 0; r < 4; ++r) {
        int e = eA[r];
        const ushort* sg = Psg + (nbase + iA[r]) * 128;
        const ushort* dg = Pdg + (nbase + jA[r]) * 128;
        const float* ef = Ab + (size_t)e * 128;
        float* yo = yOut + ((size_t)b * NE + e) * 128;
        uchar* so = sigF8 + ((size_t)b * NE + rkA[r]) * 128;
#pragma unroll
        for (int nt = 0; nt < 8; ++nt) {
            int col = nt * 16 + colb;
            float y = acc[nt][r] + b_eg[col] + b2f(sg[col]) + b2f(dg[col]);
            float sig = 1.0f / (1.0f + __expf(-y));
            yo[col] = ef[col] + y * sig;   // edge residual + silu(y)
            uint p = __builtin_amdgcn_cvt_pk_fp8_f32(sig, sig, 0, false);
            so[col] = (uchar)(p & 0xff);   // OCP e4m3 on gfx950
        }
    }
}

// ---------------- per-node streaming reduce + finalize (4-deep batched, fp8 sigma) ----------------
__global__ __launch_bounds__(256, 8) void node_reduce_kernel(
    const uchar* __restrict__ sigF8,    // [NB,NE,128] fp8 e4m3, sorted edge order
    const int* __restrict__ start,      // [NN+1]
    const int* __restrict__ jsort,      // [NE]
    const ushort* __restrict__ Pdu,     // [MROWS,128] bf16
    const ushort* __restrict__ Psu,     // [MROWS,128] bf16
    const float* __restrict__ nf,       // [MROWS,128]
    float* __restrict__ xOut)           // [MROWS,128]
{
    int task = blockIdx.x * 4 + (threadIdx.x >> 6);  // 0..16383
    int lane = threadIdx.x & 63;
    int b = task >> 12;
    int n = task & 4095;
    int s0 = start[n], s1 = start[n + 1];

    const size_t ebase = (size_t)b * NE;
    const size_t nbase = (size_t)b * NN;

    float S0 = 0.f, S1 = 0.f, Sh0 = 0.f, Sh1 = 0.f;
    int k = s0;
    for (; k + 4 <= s1; k += 4) {
        ushort us[4]; uint dv[4];
#pragma unroll
        for (int q = 0; q < 4; ++q) {
            int j = jsort[k + q];
            us[q] = *reinterpret_cast<const ushort*>(sigF8 + (ebase + k + q) * 128 + lane * 2);
            dv[q] = *reinterpret_cast<const uint*>(Pdu + (nbase + j) * 128 + lane * 2);
        }
#pragma unroll
        for (int q = 0; q < 4; ++q) {
            f32x2 sgv = __builtin_amdgcn_cvt_pk_f32_fp8((int)us[q], false);
            float da = b2f((ushort)(dv[q] & 0xffff)), db = b2f((ushort)(dv[q] >> 16));
            S0 += sgv[0]; S1 += sgv[1];
            Sh0 += da * sgv[0]; Sh1 += db * sgv[1];
        }
    }
    for (; k < s1; ++k) {
        int j = jsort[k];
        ushort u = *reinterpret_cast<const ushort*>(sigF8 + (ebase + k) * 128 + lane * 2);
        uint du2 = *reinterpret_cast<const uint*>(Pdu + (nbase + j) * 128 + lane * 2);
        f32x2 sgv = __builtin_amdgcn_cvt_pk_f32_fp8((int)u, false);
        float da = b2f((ushort)(du2 & 0xffff)), db = b2f((ushort)(du2 >> 16));
        S0 += sgv[0]; S1 += sgv[1];
        Sh0 += da * sgv[0]; Sh1 += db * sgv[1];
    }

    size_t off = (nbase + n) * 128 + lane * 2;
    uint su2 = *reinterpret_cast<const uint*>(Psu + off);
    f32x2 a = *reinterpret_cast<const f32x2*>(nf + off);
    float h0 = Sh0 / (S0 + 1e-6f);
    float h1 = Sh1 / (S1 + 1e-6f);
    float v0 = b2f((ushort)(su2 & 0xffff)) + h0;
    float v1 = b2f((ushort)(su2 >> 16)) + h1;
    f32x2 r;
    r[0] = a[0] + v0 / (1.f + __expf(-v0));
    r[1] = a[1] + v1 / (1.f + __expf(-v1));
    *reinterpret_cast<f32x2*>(xOut + off) = r;
}

extern "C" void kernel_launch(void* const* d_in, const int* in_sizes, int n_in,
                              void* d_out, int out_size, void* d_ws, size_t ws_size,
                              hipStream_t stream) {
    (void)in_sizes; (void)n_in; (void)out_size; (void)ws_size;

    const float* node_feats = (const float*)d_in[0];
    const float* edge_feats = (const float*)d_in[1];
    const int* iIdx = (const int*)d_in[2];
    const int* jIdx = (const int*)d_in[3];
    const float* Wsg = (const float*)d_in[4];  const float* bsg = (const float*)d_in[5];
    const float* Wdg = (const float*)d_in[6];  const float* bdg = (const float*)d_in[7];
    const float* Weg = (const float*)d_in[8];  const float* beg = (const float*)d_in[9];
    const float* Wsu = (const float*)d_in[10]; const float* bsu = (const float*)d_in[11];
    const float* Wdu = (const float*)d_in[12]; const float* bdu = (const float*)d_in[13];

    float* out = (float*)d_out;
    float* xOut = out;                               // [NB,NN,128]
    float* yOut = out + (size_t)MROWS * 128;         // [NB,NE,128]

    // workspace layout
    uchar* sigF8 = (uchar*)d_ws;                              // [NB*NE*128] fp8 (33.5 MB)
    ushort* P = (ushort*)(sigF8 + (size_t)NB * NE * 128);     // [4][MROWS][128] bf16 (16.8 MB)
    ushort* Wbf = P + (size_t)4 * MROWS * 128;                // [5][128][128] bf16 (160 KB)
    int* rank = (int*)(Wbf + 5 * 16384);                      // [NE]
    int* jsort = rank + NE;                                   // [NE]
    int* cnt = jsort + NE;                                    // [4096]
    int* cur = cnt + 4096;                                    // [4096]
    int* start = cur + 4096;                                  // [4097]

    hipMemsetAsync(cnt, 0, 2 * 4096 * sizeof(int), stream);   // cnt + cur

    prep_weights<<<(5 * 16384) / 256, 256, 0, stream>>>(Wsg, Wdg, Wdu, Wsu, Weg, Wbf);

    hist_kernel<<<NE / 256, 256, 0, stream>>>(iIdx, cnt);
    scan_kernel<<<1, 256, 0, stream>>>(cnt, start);
    scatter_kernel<<<NE / 256, 256, 0, stream>>>(iIdx, jIdx, start, cur, rank, jsort);

    dim3 gA(MROWS / 64, 4);
    node_proj_kernel<<<gA, 256, 0, stream>>>(node_feats, Wbf, bsg, bdg, bdu, bsu, P);

    dim3 gB(NE / 64, NB);
    edge_kernel<<<gB, 256, 0, stream>>>(edge_feats, iIdx, jIdx, rank,
                                        Wbf + (size_t)4 * 16384, beg,
                                        P,                                  // src_gate
                                        P + (size_t)1 * MROWS * 128,        // dst_gate
                                        sigF8, yOut);

    node_reduce_kernel<<<MROWS / 4, 256, 0, stream>>>(
        sigF8, start, jsort,
        P + (size_t)2 * MROWS * 128,   // dst_update
        P + (size_t)3 * MROWS * 128,   // src_update
        node_feats, xOut);
}

// Round 17
// 153.230 us; speedup vs baseline: 1.2707x; 1.2707x over previous
//
#include <hip/hip_runtime.h>
#include <hip/hip_bf16.h>

typedef __attribute__((ext_vector_type(8))) short short8;
typedef __attribute__((ext_vector_type(4))) float f32x4;
typedef __attribute__((ext_vector_type(2))) float f32x2;

#define DEVI __device__ __forceinline__

static constexpr int NB = 4;
static constexpr int NN = 4096;
static constexpr int NE = 65536;
static constexpr int MROWS = NB * NN; // 16384

DEVI short f2b(float f) {
    __hip_bfloat16 h = __float2bfloat16(f);
    return *reinterpret_cast<short*>(&h);
}
DEVI float b2f(ushort u) {
    uint v = (uint)u << 16;
    float f;
    __builtin_memcpy(&f, &v, 4);
    return f;
}

// ---------------- prep: fp32 -> bf16 weights ----------------
// order: [0]=W_src_gate [1]=W_dst_gate [2]=W_dst_update [3]=W_src_update [4]=W_edge_gate
__global__ void prep_weights(const float* __restrict__ w0, const float* __restrict__ w1,
                             const float* __restrict__ w2, const float* __restrict__ w3,
                             const float* __restrict__ w4, ushort* __restrict__ out) {
    int idx = blockIdx.x * 256 + threadIdx.x;   // 5*16384 total
    int wsel = idx >> 14;
    int off = idx & 16383;
    const float* src = wsel == 0 ? w0 : wsel == 1 ? w1 : wsel == 2 ? w2 : wsel == 3 ? w3 : w4;
    out[idx] = (ushort)f2b(src[off]);
}

// ---------------- counting sort of edges by destination i ----------------
__global__ void hist_kernel(const int* __restrict__ iIdx, int* __restrict__ cnt) {
    int e = blockIdx.x * 256 + threadIdx.x;
    atomicAdd(&cnt[iIdx[e]], 1);
}

__global__ __launch_bounds__(256) void scan_kernel(const int* __restrict__ cnt,
                                                   int* __restrict__ start) {
    __shared__ int ls[256];
    int t = threadIdx.x;
    int base = t * 16;
    int loc[16];
    int s = 0;
#pragma unroll
    for (int q = 0; q < 16; ++q) { loc[q] = s; s += cnt[base + q]; }
    ls[t] = s;
    __syncthreads();
    for (int off = 1; off < 256; off <<= 1) {
        int v = (t >= off) ? ls[t - off] : 0;
        __syncthreads();
        ls[t] += v;
        __syncthreads();
    }
    int ex = ls[t] - s;   // exclusive prefix of this thread's chunk
#pragma unroll
    for (int q = 0; q < 16; ++q) start[base + q] = ex + loc[q];
    if (t == 255) start[4096] = ex + s;
}

// rank[e] = sorted position of edge e; jsort[pos] = jIdx[e]
__global__ void scatter_kernel(const int* __restrict__ iIdx, const int* __restrict__ jIdx,
                               const int* __restrict__ start, int* __restrict__ cur,
                               int* __restrict__ rank, int* __restrict__ jsort) {
    int e = blockIdx.x * 256 + threadIdx.x;
    int iv = iIdx[e];
    int pos = start[iv] + atomicAdd(&cur[iv], 1);
    rank[e] = pos;
    jsort[pos] = jIdx[e];
}

// Stage one 128x128 bf16 weight into LDS, XOR-swizzled (byte ^= (n&7)<<4). 256 threads.
DEVI void stage_W256(const ushort* __restrict__ Wg, ushort* Wl, int tid) {
    int n = tid >> 1;           // row 0..127
    int kh = (tid & 1) * 64;    // half-row in bf16 elems
#pragma unroll
    for (int c = 0; c < 8; ++c) {
        int k = kh + c * 8;
        short8 v = *reinterpret_cast<const short8*>(Wg + n * 128 + k);
        int byt = (n * 256 + k * 2) ^ ((n & 7) << 4);
        *reinterpret_cast<short8*>(reinterpret_cast<char*>(Wl) + byt) = v;
    }
}

// Same staging with 512 threads.
DEVI void stage_W512(const ushort* __restrict__ Wg, ushort* Wl, int tid) {
    int n = tid >> 2;           // row 0..127
    int kq = (tid & 3) * 32;    // quarter-row in bf16 elems
#pragma unroll
    for (int c = 0; c < 4; ++c) {
        int k = kq + c * 8;
        short8 v = *reinterpret_cast<const short8*>(Wg + n * 128 + k);
        int byt = (n * 256 + k * 2) ^ ((n & 7) << 4);
        *reinterpret_cast<short8*>(reinterpret_cast<char*>(Wl) + byt) = v;
    }
}

// Load this lane's A fragments (K=128 split in 4 ks-slices) from a fp32 row.
DEVI void load_afrag(const float* __restrict__ rowptr, int kgrp, short8 afrag[4]) {
#pragma unroll
    for (int ks = 0; ks < 4; ++ks) {
        int k0 = ks * 32 + kgrp * 8;
        f32x4 lo = *reinterpret_cast<const f32x4*>(rowptr + k0);
        f32x4 hi = *reinterpret_cast<const f32x4*>(rowptr + k0 + 4);
        short8 a;
#pragma unroll
        for (int q = 0; q < 4; ++q) a[q] = f2b(lo[q]);
#pragma unroll
        for (int q = 0; q < 4; ++q) a[4 + q] = f2b(hi[q]);
        afrag[ks] = a;
    }
}

// acc[nt]: row = wv*16 + (lane>>4)*4 + r, col = nt*16 + (lane&15). B from XOR-swizzled LDS.
DEVI void mfma_frags(const short8 afrag[4], const ushort* __restrict__ Wl,
                     int lane, f32x4 acc[8]) {
    const int colb = lane & 15;
    const int kgrp = lane >> 4;
#pragma unroll
    for (int nt = 0; nt < 8; ++nt) acc[nt] = f32x4{0.f, 0.f, 0.f, 0.f};
#pragma unroll
    for (int ks = 0; ks < 4; ++ks) {
#pragma unroll
        for (int nt = 0; nt < 8; ++nt) {
            int n = nt * 16 + colb;
            int byt = (n * 256 + (ks * 32 + kgrp * 8) * 2) ^ ((n & 7) << 4);
            short8 bfrag = *reinterpret_cast<const short8*>(
                reinterpret_cast<const char*>(Wl) + byt);
            acc[nt] = __builtin_amdgcn_mfma_f32_16x16x32_bf16(afrag[ks], bfrag, acc[nt], 0, 0, 0);
        }
    }
}

// ---------------- node projections: P[w] = bf16(node_feats @ W[w]^T + b[w]) ----------------
// Round-6/10/12 proven version (LDS-staged W, blockIdx.y = weight index).
__global__ __launch_bounds__(256) void node_proj_kernel(
    const float* __restrict__ node_feats,  // [MROWS,128]
    const ushort* __restrict__ Wbf,        // [5][128][128] bf16
    const float* __restrict__ bias0, const float* __restrict__ bias1,
    const float* __restrict__ bias2, const float* __restrict__ bias3,
    ushort* __restrict__ P)                // [4][MROWS][128] bf16
{
    __shared__ ushort Wl[128 * 128];  // 32 KB
    const int widx = blockIdx.y;
    const int row0 = blockIdx.x * 64;
    const int tid = threadIdx.x;

    stage_W256(Wbf + (size_t)widx * 16384, Wl, tid);
    __syncthreads();

    const int lane = tid & 63, wv = tid >> 6;
    const int colb = lane & 15, kgrp = lane >> 4;
    short8 afrag[4];
    load_afrag(node_feats + (size_t)(row0 + wv * 16 + colb) * 128, kgrp, afrag);
    f32x4 acc[8];
    mfma_frags(afrag, Wl, lane, acc);

    const float* bias = widx == 0 ? bias0 : widx == 1 ? bias1 : widx == 2 ? bias2 : bias3;
    ushort* Po = P + (size_t)widx * MROWS * 128;
#pragma unroll
    for (int r = 0; r < 4; ++r) {
        int row = row0 + wv * 16 + kgrp * 4 + r;
#pragma unroll
        for (int nt = 0; nt < 8; ++nt) {
            int col = nt * 16 + colb;
            Po[(size_t)row * 128 + col] = (ushort)f2b(acc[nt][r] + bias[col]);
        }
    }
}

// ---------------- fused edge kernel: round-12/14/15 proven + fp8 sigma store ----------------
// 8 waves share one LDS W stage; (512,4); rank-sorted sigma write in OCP e4m3 (1 B/elem).
__global__ __launch_bounds__(512, 4) void edge_kernel(
    const float* __restrict__ edge_feats,  // [NB,NE,128]
    const int* __restrict__ iIdx, const int* __restrict__ jIdx,
    const int* __restrict__ rank,          // [NE] sorted position of edge e
    const ushort* __restrict__ Weg,        // [128][128] bf16 (edge gate)
    const float* __restrict__ b_eg,
    const ushort* __restrict__ Psg, const ushort* __restrict__ Pdg,
    uchar* __restrict__ sigF8,             // [NB,NE,128] fp8 e4m3, SORTED edge order
    float* __restrict__ yOut)              // [NB,NE,128]
{
    __shared__ ushort Wl[128 * 128];  // 32 KB, read-only after stage
    const int b = blockIdx.y;
    const int e0 = blockIdx.x * 128;
    const int tid = threadIdx.x;

    stage_W512(Weg, Wl, tid);
    __syncthreads();

    const int lane = tid & 63, wv = tid >> 6;   // wv 0..7
    const int colb = lane & 15, kgrp = lane >> 4;
    const float* Ab = edge_feats + (size_t)b * NE * 128;
    const size_t nbase = (size_t)b * NN;

    short8 afrag[4];
    load_afrag(Ab + (size_t)(e0 + wv * 16 + colb) * 128, kgrp, afrag);

    // hoisted epilogue indices (round-14, neutral but harmless)
    int eA[4], iA[4], jA[4], rkA[4];
#pragma unroll
    for (int r = 0; r < 4; ++r) {
        int e = e0 + wv * 16 + kgrp * 4 + r;
        eA[r] = e;
        iA[r] = iIdx[e];
        jA[r] = jIdx[e];
        rkA[r] = rank[e];
    }

    f32x4 acc[8];
    mfma_frags(afrag, Wl, lane, acc);

    // epilogue in fragment layout (round-2/5/6/12 proven)
#pragma unroll
    for (int r = 0; r < 4; ++r) {
        int e = eA[r];
        const ushort* sg = Psg + (nbase + iA[r]) * 128;
        const ushort* dg = Pdg + (nbase + jA[r]) * 128;
        const float* ef = Ab + (size_t)e * 128;
        float* yo = yOut + ((size_t)b * NE + e) * 128;
        uchar* so = sigF8 + ((size_t)b * NE + rkA[r]) * 128;
#pragma unroll
        for (int nt = 0; nt < 8; ++nt) {
            int col = nt * 16 + colb;
            float y = acc[nt][r] + b_eg[col] + b2f(sg[col]) + b2f(dg[col]);
            float sig = 1.0f / (1.0f + __expf(-y));
            yo[col] = ef[col] + y * sig;   // edge residual + silu(y)
            uint p = __builtin_amdgcn_cvt_pk_fp8_f32(sig, sig, 0, false);
            so[col] = (uchar)(p & 0xff);   // OCP e4m3 on gfx950
        }
    }
}

// ---------------- per-node streaming reduce + finalize (4-deep batched, fp8 sigma) ----------------
__global__ __launch_bounds__(256, 8) void node_reduce_kernel(
    const uchar* __restrict__ sigF8,    // [NB,NE,128] fp8 e4m3, sorted edge order
    const int* __restrict__ start,      // [NN+1]
    const int* __restrict__ jsort,      // [NE]
    const ushort* __restrict__ Pdu,     // [MROWS,128] bf16
    const ushort* __restrict__ Psu,     // [MROWS,128] bf16
    const float* __restrict__ nf,       // [MROWS,128]
    float* __restrict__ xOut)           // [MROWS,128]
{
    int task = blockIdx.x * 4 + (threadIdx.x >> 6);  // 0..16383
    int lane = threadIdx.x & 63;
    int b = task >> 12;
    int n = task & 4095;
    int s0 = start[n], s1 = start[n + 1];

    const size_t ebase = (size_t)b * NE;
    const size_t nbase = (size_t)b * NN;

    float S0 = 0.f, S1 = 0.f, Sh0 = 0.f, Sh1 = 0.f;
    int k = s0;
    for (; k + 4 <= s1; k += 4) {
        ushort us[4]; uint dv[4];
#pragma unroll
        for (int q = 0; q < 4; ++q) {
            int j = jsort[k + q];
            us[q] = *reinterpret_cast<const ushort*>(sigF8 + (ebase + k + q) * 128 + lane * 2);
            dv[q] = *reinterpret_cast<const uint*>(Pdu + (nbase + j) * 128 + lane * 2);
        }
#pragma unroll
        for (int q = 0; q < 4; ++q) {
            f32x2 sgv = __builtin_amdgcn_cvt_pk_f32_fp8((int)us[q], false);
            float da = b2f((ushort)(dv[q] & 0xffff)), db = b2f((ushort)(dv[q] >> 16));
            S0 += sgv[0]; S1 += sgv[1];
            Sh0 += da * sgv[0]; Sh1 += db * sgv[1];
        }
    }
    for (; k < s1; ++k) {
        int j = jsort[k];
        ushort u = *reinterpret_cast<const ushort*>(sigF8 + (ebase + k) * 128 + lane * 2);
        uint du2 = *reinterpret_cast<const uint*>(Pdu + (nbase + j) * 128 + lane * 2);
        f32x2 sgv = __builtin_amdgcn_cvt_pk_f32_fp8((int)u, false);
        float da = b2f((ushort)(du2 & 0xffff)), db = b2f((ushort)(du2 >> 16));
        S0 += sgv[0]; S1 += sgv[1];
        Sh0 += da * sgv[0]; Sh1 += db * sgv[1];
    }

    size_t off = (nbase + n) * 128 + lane * 2;
    uint su2 = *reinterpret_cast<const uint*>(Psu + off);
    f32x2 a = *reinterpret_cast<const f32x2*>(nf + off);
    float h0 = Sh0 / (S0 + 1e-6f);
    float h1 = Sh1 / (S1 + 1e-6f);
    float v0 = b2f((ushort)(su2 & 0xffff)) + h0;
    float v1 = b2f((ushort)(su2 >> 16)) + h1;
    f32x2 r;
    r[0] = a[0] + v0 / (1.f + __expf(-v0));
    r[1] = a[1] + v1 / (1.f + __expf(-v1));
    *reinterpret_cast<f32x2*>(xOut + off) = r;
}

extern "C" void kernel_launch(void* const* d_in, const int* in_sizes, int n_in,
                              void* d_out, int out_size, void* d_ws, size_t ws_size,
                              hipStream_t stream) {
    (void)in_sizes; (void)n_in; (void)out_size; (void)ws_size;

    const float* node_feats = (const float*)d_in[0];
    const float* edge_feats = (const float*)d_in[1];
    const int* iIdx = (const int*)d_in[2];
    const int* jIdx = (const int*)d_in[3];
    const float* Wsg = (const float*)d_in[4];  const float* bsg = (const float*)d_in[5];
    const float* Wdg = (const float*)d_in[6];  const float* bdg = (const float*)d_in[7];
    const float* Weg = (const float*)d_in[8];  const float* beg = (const float*)d_in[9];
    const float* Wsu = (const float*)d_in[10]; const float* bsu = (const float*)d_in[11];
    const float* Wdu = (const float*)d_in[12]; const float* bdu = (const float*)d_in[13];

    float* out = (float*)d_out;
    float* xOut = out;                               // [NB,NN,128]
    float* yOut = out + (size_t)MROWS * 128;         // [NB,NE,128]

    // workspace layout
    uchar* sigF8 = (uchar*)d_ws;                              // [NB*NE*128] fp8 (33.5 MB)
    ushort* P = (ushort*)(sigF8 + (size_t)NB * NE * 128);     // [4][MROWS][128] bf16 (16.8 MB)
    ushort* Wbf = P + (size_t)4 * MROWS * 128;                // [5][128][128] bf16 (160 KB)
    int* rank = (int*)(Wbf + 5 * 16384);                      // [NE]
    int* jsort = rank + NE;                                   // [NE]
    int* cnt = jsort + NE;                                    // [4096]
    int* cur = cnt + 4096;                                    // [4096]
    int* start = cur + 4096;                                  // [4097]

    hipMemsetAsync(cnt, 0, 2 * 4096 * sizeof(int), stream);   // cnt + cur

    prep_weights<<<(5 * 16384) / 256, 256, 0, stream>>>(Wsg, Wdg, Wdu, Wsu, Weg, Wbf);

    hist_kernel<<<NE / 256, 256, 0, stream>>>(iIdx, cnt);
    scan_kernel<<<1, 256, 0, stream>>>(cnt, start);
    scatter_kernel<<<NE / 256, 256, 0, stream>>>(iIdx, jIdx, start, cur, rank, jsort);

    dim3 gA(MROWS / 64, 4);
    node_proj_kernel<<<gA, 256, 0, stream>>>(node_feats, Wbf, bsg, bdg, bdu, bsu, P);

    dim3 gB(NE / 128, NB);
    edge_kernel<<<gB, 512, 0, stream>>>(edge_feats, iIdx, jIdx, rank,
                                        Wbf + (size_t)4 * 16384, beg,
                                        P,                                  // src_gate
                                        P + (size_t)1 * MROWS * 128,        // dst_gate
                                        sigF8, yOut);

    node_reduce_kernel<<<MROWS / 4, 256, 0, stream>>>(
        sigF8, start, jsort,
        P + (size_t)2 * MROWS * 128,   // dst_update
        P + (size_t)3 * MROWS * 128,   // src_update
        node_feats, xOut);
}